// Round 11
// baseline (71.578 us; speedup 1.0000x reference)
//
#include <hip/hip_runtime.h>
#include <math.h>

#define N_ATOMS 512
#define N_MOL   16
#define HIDDEN  128
#define FILTERS 128
#define NUM_RBF 50
#define CUTOFF  10.0f
#define N_LAYERS 3

#define KB4    4096                  // nearest-neighbor bins over [0,10]
#define NB4    (KB4 + 1)             // rows 0..4096 (row 4096 = zeros via env)
#define TBPL   65                    // table blocks per layer (65*64 >= 4097 bins)
#define TBLK   (N_LAYERS * TBPL)     // 195 table blocks
#define EMBB   16                    // emb blocks, 32 atoms each
#define PI_F   3.14159265358979f
#define DINV   409.6f                // KB4 / CUTOFF
#define DSTEP  (CUTOFF / (float)KB4)

__device__ __forceinline__ unsigned short f2bf(float v) {
    unsigned u = __float_as_uint(v);
    u += 0x7fffu + ((u >> 16) & 1u);     // round-to-nearest-even
    return (unsigned short)(u >> 16);
}

// ============ front: filter tables (nearest-bin, 64 bins/block) ∥ embedding+xj0 ============
__global__ void __launch_bounds__(256) k_front(
        const int* __restrict__ an, const float* __restrict__ emb,
        const float* __restrict__ d1w, const float* __restrict__ d1b,
        const float* __restrict__ fw1, const float* __restrict__ fb1,
        const float* __restrict__ fw2, const float* __restrict__ fb2,
        float* __restrict__ x, unsigned short* __restrict__ xj,
        unsigned short* __restrict__ tab, float* __restrict__ molsum,
        int* __restrict__ done) {
    __shared__ float          s_rbf[64][NUM_RBF];        // 12.8 KB (table)
    __shared__ unsigned short s_h2[64][FILTERS];         // 16 KB bf16 h (table)
    __shared__ __align__(16) float s_row[32][HIDDEN];    // 16 KB (emb)
    __shared__ int            s_an[32];
    int bid = blockIdx.x, t = threadIdx.x;

    if (bid == 0) {                                      // zero pool accumulators each call
        for (int idx = t; idx < N_MOL * HIDDEN; idx += 256) molsum[idx] = 0.f;
        if (t == 0) *done = 0;
    }

    if (bid < TBLK) {
        // ---------------- filter table: 4 waves x 16 bins ----------------
        int l = bid / TBPL, bx = bid - l * TBPL;
        int bin0 = bx * 64;
        const float* w1g = fw1 + (size_t)l * NUM_RBF * FILTERS;
        const float* w2g = fw2 + (size_t)l * FILTERS * FILTERS;
        for (int idx = t; idx < 64 * NUM_RBF; idx += 256) {
            int lb = idx / NUM_RBF, r = idx - lb * NUM_RBF;
            float dd = (bin0 + lb) * DSTEP;
            float cr = r * (CUTOFF / (float)(NUM_RBF - 1));
            float xx = dd - cr;
            s_rbf[lb][r] = __expf(-xx * xx * 12.5f);     // 1/(2*w^2), w = 0.2
        }
        __syncthreads();
        int wv = t >> 6, ln = t & 63;
        int c0 = ln, c1 = ln + 64;
        float h0[16], h1[16];
        float b1v0 = fb1[l * FILTERS + c0], b1v1 = fb1[l * FILTERS + c1];
        #pragma unroll
        for (int bb = 0; bb < 16; bb++) { h0[bb] = b1v0; h1[bb] = b1v1; }
        for (int r = 0; r < NUM_RBF; r++) {
            float w0 = w1g[r * FILTERS + c0];
            float w1v = w1g[r * FILTERS + c1];
            #pragma unroll
            for (int bb = 0; bb < 16; bb++) {
                float rb = s_rbf[wv * 16 + bb][r];
                h0[bb] = fmaf(rb, w0, h0[bb]);
                h1[bb] = fmaf(rb, w1v, h1[bb]);
            }
        }
        #pragma unroll
        for (int bb = 0; bb < 16; bb++) {
            float a0 = h0[bb], a1 = h1[bb];
            s_h2[wv * 16 + bb][c0] = f2bf(a0 / (1.f + __expf(-a0)));   // silu, bf16
            s_h2[wv * 16 + bb][c1] = f2bf(a1 / (1.f + __expf(-a1)));
        }
        __syncthreads();
        float o0[16], o1[16];
        float b2v0 = fb2[l * FILTERS + c0], b2v1 = fb2[l * FILTERS + c1];
        #pragma unroll
        for (int bb = 0; bb < 16; bb++) { o0[bb] = b2v0; o1[bb] = b2v1; }
        const unsigned int* s_h2u = (const unsigned int*)s_h2;
        for (int hp = 0; hp < 64; hp++) {               // hh pair = {2hp, 2hp+1}
            float wa0 = w2g[(2 * hp) * FILTERS + c0];
            float wa1 = w2g[(2 * hp) * FILTERS + c1];
            float wb0 = w2g[(2 * hp + 1) * FILTERS + c0];
            float wb1 = w2g[(2 * hp + 1) * FILTERS + c1];
            #pragma unroll
            for (int bb = 0; bb < 16; bb++) {
                unsigned int hu = s_h2u[(wv * 16 + bb) * 64 + hp];    // broadcast
                float hx = __uint_as_float(hu << 16);
                float hy = __uint_as_float(hu & 0xffff0000u);
                o0[bb] = fmaf(hx, wa0, o0[bb]);  o0[bb] = fmaf(hy, wb0, o0[bb]);
                o1[bb] = fmaf(hx, wa1, o1[bb]);  o1[bb] = fmaf(hy, wb1, o1[bb]);
            }
        }
        size_t base = (size_t)l * NB4 * FILTERS;
        #pragma unroll
        for (int bb = 0; bb < 16; bb++) {
            int bin = bin0 + wv * 16 + bb;
            if (bin <= KB4) {
                float dd = bin * DSTEP;
                float env = (bin >= KB4) ? 0.f : 0.5f * (__cosf(dd * (PI_F / CUTOFF)) + 1.f);
                tab[base + (size_t)bin * FILTERS + c0] = f2bf(o0[bb] * env);
                tab[base + (size_t)bin * FILTERS + c1] = f2bf(o1[bb] * env);
            }
        }
    } else {
        // ---------------- embedding gather + xj0 = x @ d1w[0] + d1b[0], 32 atoms ----------------
        int eb = bid - TBLK;
        int i0 = eb * 32;
        if (t < 32) s_an[t] = an[i0 + t];
        __syncthreads();
        for (int idx = t; idx < 32 * HIDDEN; idx += 256) {
            int a = idx >> 7, c = idx & 127;
            float v = emb[(size_t)s_an[a] * HIDDEN + c];
            s_row[a][c] = v;
            x[(size_t)(i0 + a) * HIDDEN + c] = v;
        }
        __syncthreads();
        int cq = t & 31, ag = t >> 5;                    // c = 4*cq+cc ; atoms ag*4+aa
        float o[4][4];
        float4 bv = *(const float4*)(d1b + 4 * cq);
        float bva[4] = { bv.x, bv.y, bv.z, bv.w };
        #pragma unroll
        for (int aa = 0; aa < 4; aa++)
            #pragma unroll
            for (int cc = 0; cc < 4; cc++) o[aa][cc] = bva[cc];
        #pragma unroll 4
        for (int h = 0; h < HIDDEN; h += 2) {
            float4 wA = *(const float4*)(d1w + (size_t)h * FILTERS + 4 * cq);
            float4 wB = *(const float4*)(d1w + (size_t)(h + 1) * FILTERS + 4 * cq);
            float wa[4] = { wA.x, wA.y, wA.z, wA.w };
            float wb[4] = { wB.x, wB.y, wB.z, wB.w };
            #pragma unroll
            for (int aa = 0; aa < 4; aa++) {
                float2 hp = *(const float2*)(&s_row[ag * 4 + aa][h]);
                #pragma unroll
                for (int cc = 0; cc < 4; cc++) {
                    o[aa][cc] = fmaf(hp.x, wa[cc], o[aa][cc]);
                    o[aa][cc] = fmaf(hp.y, wb[cc], o[aa][cc]);
                }
            }
        }
        #pragma unroll
        for (int aa = 0; aa < 4; aa++) {
            int i = i0 + ag * 4 + aa;
            #pragma unroll
            for (int cp = 0; cp < 2; cp++) {
                unsigned int pk = (unsigned)f2bf(o[aa][2 * cp]) |
                                  ((unsigned)f2bf(o[aa][2 * cp + 1]) << 16);
                *(unsigned int*)(xj + (size_t)i * FILTERS + 4 * cq + 2 * cp) = pk;
            }
        }
    }
}

// ======== layer: 2 j-rows per block (xj read once); nearest-bin gather (4 B/lane) ========
// LAST merges the pool via device atomics (no threadfence — R9's fence was the regression).
template<int LAST>
__global__ void __launch_bounds__(512) k_layer(const float* __restrict__ pos,
        const unsigned int* __restrict__ tabl, const unsigned int* __restrict__ xj_in,
        float* __restrict__ x, const float* __restrict__ w2, const float* __restrict__ b2,
        const float* __restrict__ w1n, const float* __restrict__ b1n,
        unsigned short* __restrict__ xj_out,
        const int* __restrict__ batch, float* __restrict__ molsum, int* __restrict__ done,
        const float* __restrict__ ow1, const float* __restrict__ ob1,
        const float* __restrict__ ow2, const float* __restrict__ ob2,
        float* __restrict__ out) {
    int bid = blockIdx.x, t = threadIdx.x;
    int j0 = 2 * bid, j1 = j0 + 1;
    int wv = t >> 6, e = t & 63;
    __shared__ unsigned int s_bin[N_ATOMS];              // 2 KB: bins to j0 | j1<<16
    __shared__ float s_part[2][8][FILTERS];              // 8 KB
    __shared__ float s_red[4][FILTERS];
    __shared__ float s_agg[2][FILTERS];
    __shared__ float s_xn[2][HIDDEN];
    __shared__ int   s_cnt;
    {   // two distances per thread
        float px = pos[3*t], py = pos[3*t+1], pz = pos[3*t+2];
        float ax = pos[3*j0], ay = pos[3*j0+1], az = pos[3*j0+2];
        float bx = pos[3*j1], by = pos[3*j1+1], bz = pos[3*j1+2];
        float d0 = sqrtf((px-ax)*(px-ax) + (py-ay)*(py-ay) + (pz-az)*(pz-az));
        float d1 = sqrtf((px-bx)*(px-bx) + (py-by)*(py-by) + (pz-bz)*(pz-bz));
        unsigned int b0 = (t == j0 || d0 >= CUTOFF) ? KB4 : (unsigned)(int)fmaf(d0, DINV, 0.5f);
        unsigned int b1 = (t == j1 || d1 >= CUTOFF) ? KB4 : (unsigned)(int)fmaf(d1, DINV, 0.5f);
        if (b0 > KB4) b0 = KB4;
        if (b1 > KB4) b1 = KB4;
        s_bin[t] = b0 | (b1 << 16);
    }
    int c = t & 127, seg = t >> 7, jj = seg >> 1, sub = seg & 1;
    float xold = (sub == 0) ? x[(size_t)(jj ? j1 : j0) * HIDDEN + c] : 0.f;
    __syncthreads();
    // ---- aggregation: wave wv covers i in [wv*64,+64) for BOTH j's ----
    float a0e = 0.f, a0o = 0.f, a1e = 0.f, a1o = 0.f;
    int i0 = wv * 64;
    for (int ii = 0; ii < 64; ii += 4) {
        #pragma unroll
        for (int r = 0; r < 4; r++) {
            unsigned int pk = s_bin[i0 + ii + r];
            unsigned int bb0 = pk & 0xffffu, bb1 = pk >> 16;
            unsigned int xu = xj_in[(size_t)(i0 + ii + r) * 64 + e];
            unsigned int f0 = tabl[(size_t)bb0 * 64 + e];
            unsigned int f1 = tabl[(size_t)bb1 * 64 + e];
            float xe = __uint_as_float(xu << 16), xo = __uint_as_float(xu & 0xffff0000u);
            float p0e = __uint_as_float(f0 << 16), p0o = __uint_as_float(f0 & 0xffff0000u);
            float p1e = __uint_as_float(f1 << 16), p1o = __uint_as_float(f1 & 0xffff0000u);
            a0e = fmaf(xe, p0e, a0e);  a0o = fmaf(xo, p0o, a0o);
            a1e = fmaf(xe, p1e, a1e);  a1o = fmaf(xo, p1o, a1o);
        }
    }
    s_part[0][wv][2*e] = a0e;  s_part[0][wv][2*e+1] = a0o;
    s_part[1][wv][2*e] = a1e;  s_part[1][wv][2*e+1] = a1o;
    __syncthreads();
    if (t < 256) {
        int pj = t >> 7, cc = t & 127;
        float s = 0.f;
        #pragma unroll
        for (int w8 = 0; w8 < 8; w8++) s += s_part[pj][w8][cc];
        s_agg[pj][cc] = s;
    }
    __syncthreads();
    // ---- x update: seg {0,1}->j0, {2,3}->j1; sub splits the 128-dot 64/64 ----
    float v = 0.f;
    #pragma unroll 8
    for (int ff = sub * 64; ff < sub * 64 + 64; ff++)
        v = fmaf(s_agg[jj][ff], w2[(size_t)ff * HIDDEN + c], v);
    s_red[seg][c] = v;
    __syncthreads();
    float xnew = 0.f;
    if (sub == 0) {
        xnew = xold + b2[c] + s_red[jj*2][c] + s_red[jj*2+1][c];
        x[(size_t)(jj ? j1 : j0) * HIDDEN + c] = xnew;
        s_xn[jj][c] = xnew;
    }
    __syncthreads();
    if (!LAST) {
        float a2 = 0.f;
        #pragma unroll 8
        for (int hh = sub * 64; hh < sub * 64 + 64; hh++)
            a2 = fmaf(s_xn[jj][hh], w1n[(size_t)hh * FILTERS + c], a2);
        s_red[seg][c] = a2;
        __syncthreads();
        if (sub == 0)
            xj_out[(size_t)(jj ? j1 : j0) * FILTERS + c] =
                f2bf(b1n[c] + s_red[jj*2][c] + s_red[jj*2+1][c]);
    } else {
        // ---- pool tail: device atomics; __syncthreads drains vmcnt before done++ ----
        if (sub == 0) atomicAdd(&molsum[(size_t)batch[jj ? j1 : j0] * HIDDEN + c], xnew);
        __syncthreads();                                  // compiler emits vmcnt(0) drain here
        if (t == 0) atomicAdd(done, 1);
        if (bid < N_MOL) {
            int m = bid;
            if (t == 0) {
                while (atomicAdd(done, 0) < N_ATOMS / 2) __builtin_amdgcn_s_sleep(16);
                s_cnt = 0;
            }
            __syncthreads();
            atomicAdd(&s_cnt, (batch[t] == m) ? 1 : 0);
            __syncthreads();
            int cnt = s_cnt;
            if (t < HIDDEN)
                s_xn[0][t] = atomicAdd(&molsum[(size_t)m * HIDDEN + t], 0.f)
                           / (float)(cnt > 0 ? cnt : 1);
            __syncthreads();
            int o = t & 63, sl = t >> 6;                  // 8 slices x 16 terms
            float a = 0.f;
            #pragma unroll 8
            for (int h = sl * 16; h < sl * 16 + 16; h++)
                a = fmaf(s_xn[0][h], ow1[h * 64 + o], a);
            float* sr = (float*)s_part;                   // reuse as [8][64]
            sr[sl * 64 + o] = a;
            __syncthreads();
            if (t < 64) {
                float vv = ob1[t];
                #pragma unroll
                for (int s8 = 0; s8 < 8; s8++) vv += sr[s8 * 64 + t];
                float hh = vv / (1.f + __expf(-vv));      // silu
                float d2 = hh * ow2[t];
                for (int off = 32; off > 0; off >>= 1) d2 += __shfl_down(d2, off, 64);
                if (t == 0) out[m] = d2 + ob2[0];
            }
        }
    }
}

extern "C" void kernel_launch(void* const* d_in, const int* in_sizes, int n_in,
                              void* d_out, int out_size, void* d_ws, size_t ws_size,
                              hipStream_t stream) {
    const int*   an    = (const int*)  d_in[0];
    const float* pos   = (const float*)d_in[1];
    const int*   batch = (const int*)  d_in[2];
    const float* emb   = (const float*)d_in[3];
    const float* fw1   = (const float*)d_in[4];
    const float* fb1   = (const float*)d_in[5];
    const float* fw2   = (const float*)d_in[6];
    const float* fb2   = (const float*)d_in[7];
    const float* d1w   = (const float*)d_in[8];
    const float* d1b   = (const float*)d_in[9];
    const float* d2w   = (const float*)d_in[10];
    const float* d2b   = (const float*)d_in[11];
    const float* ow1   = (const float*)d_in[12];
    const float* ob1   = (const float*)d_in[13];
    const float* ow2   = (const float*)d_in[14];
    const float* ob2   = (const float*)d_in[15];
    float* out = (float*)d_out;

    float*          x    = (float*)d_ws;                               // 256 KB
    unsigned short* xjA  = (unsigned short*)(x + N_ATOMS * HIDDEN);    // 128 KB
    unsigned short* xjB  = xjA + (size_t)N_ATOMS * FILTERS;            // 128 KB
    unsigned short* tab  = xjB + (size_t)N_ATOMS * FILTERS;            // 3*4097*128*2B = 3.07 MB
    float*          mols = (float*)(tab + (size_t)N_LAYERS * NB4 * FILTERS);
    int*            done = (int*)(mols + N_MOL * HIDDEN);

    k_front<<<TBLK + EMBB, 256, 0, stream>>>(
        an, emb, d1w, d1b, fw1, fb1, fw2, fb2, x, xjA, tab, mols, done);

    const unsigned int* t0 = (const unsigned int*)(tab + (size_t)0 * NB4 * FILTERS);
    const unsigned int* t1 = (const unsigned int*)(tab + (size_t)1 * NB4 * FILTERS);
    const unsigned int* t2 = (const unsigned int*)(tab + (size_t)2 * NB4 * FILTERS);

    k_layer<0><<<N_ATOMS/2, 512, 0, stream>>>(pos, t0, (const unsigned int*)xjA, x,
        d2w + (size_t)0*FILTERS*HIDDEN, d2b + (size_t)0*HIDDEN,
        d1w + (size_t)1*HIDDEN*FILTERS, d1b + (size_t)1*FILTERS, xjB,
        batch, mols, done, ow1, ob1, ow2, ob2, out);
    k_layer<0><<<N_ATOMS/2, 512, 0, stream>>>(pos, t1, (const unsigned int*)xjB, x,
        d2w + (size_t)1*FILTERS*HIDDEN, d2b + (size_t)1*HIDDEN,
        d1w + (size_t)2*HIDDEN*FILTERS, d1b + (size_t)2*FILTERS, xjA,
        batch, mols, done, ow1, ob1, ow2, ob2, out);
    k_layer<1><<<N_ATOMS/2, 512, 0, stream>>>(pos, t2, (const unsigned int*)xjA, x,
        d2w + (size_t)2*FILTERS*HIDDEN, d2b + (size_t)2*HIDDEN,
        d1w, d1b, xjB,
        batch, mols, done, ow1, ob1, ow2, ob2, out);
}

// Round 12
// 63.926 us; speedup vs baseline: 1.1197x; 1.1197x over previous
//
#include <hip/hip_runtime.h>
#include <math.h>

#define N_ATOMS 512
#define N_MOL   16
#define HIDDEN  128
#define FILTERS 128
#define NUM_RBF 50
#define CUTOFF  10.0f
#define N_LAYERS 3

#define KB4    4096                  // nearest-neighbor bins over [0,10]
#define NB4    (KB4 + 1)             // rows 0..4096 (row 4096 = zeros via env)
#define TBPL   129                   // table blocks per layer (129*32 >= 4097 bins)
#define TBLK   (N_LAYERS * TBPL)     // 387 table blocks
#define EMBB   16                    // emb blocks, 32 atoms each
#define PI_F   3.14159265358979f
#define DINV   409.6f                // KB4 / CUTOFF
#define DSTEP  (CUTOFF / (float)KB4)

__device__ __forceinline__ unsigned short f2bf(float v) {
    unsigned u = __float_as_uint(v);
    u += 0x7fffu + ((u >> 16) & 1u);     // round-to-nearest-even
    return (unsigned short)(u >> 16);
}

// ====== front: filter tables as per-block fused GEMM (32 bins/block) ∥ embedding+xj0 ======
// Table block: rbf->H=silu(rbf@w1+b1) in f32 LDS (4x4 reg tile), then H @ w2 GEMM with
// float4 per-lane weight loads + LDS float2 broadcasts (R5-emb pattern, ~2 LDS/32 FMA).
__global__ void __launch_bounds__(256) k_front(
        const int* __restrict__ an, const float* __restrict__ emb,
        const float* __restrict__ d1w, const float* __restrict__ d1b,
        const float* __restrict__ fw1, const float* __restrict__ fb1,
        const float* __restrict__ fw2, const float* __restrict__ fb2,
        float* __restrict__ x, unsigned short* __restrict__ xj,
        unsigned short* __restrict__ tab, float* __restrict__ molsum,
        int* __restrict__ done) {
    __shared__ float s_rbf[32][NUM_RBF];                 // 6.4 KB (table)
    __shared__ __align__(16) float s_H[32][132];         // 16.9 KB f32 h (table)
    __shared__ __align__(16) float s_row[32][HIDDEN];    // 16 KB (emb)
    __shared__ int   s_an[32];
    int bid = blockIdx.x, t = threadIdx.x;

    if (bid == 0) {                                      // zero pool accumulators each call
        for (int idx = t; idx < N_MOL * HIDDEN; idx += 256) molsum[idx] = 0.f;
        if (t == 0) *done = 0;
    }

    int cq = t & 31, ag = t >> 5;                        // c = 4*cq+cc ; rows ag*4+aa

    if (bid < TBLK) {
        // ---------------- filter table: 32 bins, fused rbf->silu->GEMM ----------------
        int l = bid / TBPL, bx = bid - l * TBPL;
        int bin0 = bx * 32;
        const float* w1g = fw1 + (size_t)l * NUM_RBF * FILTERS;
        const float* w2g = fw2 + (size_t)l * FILTERS * FILTERS;
        for (int idx = t; idx < 32 * NUM_RBF; idx += 256) {
            int lb = idx / NUM_RBF, r = idx - lb * NUM_RBF;
            float dd = (bin0 + lb) * DSTEP;
            float cr = r * (CUTOFF / (float)(NUM_RBF - 1));
            float xx = dd - cr;
            s_rbf[lb][r] = __expf(-xx * xx * 12.5f);     // 1/(2*w^2), w = 0.2
        }
        __syncthreads();
        // H = silu(rbf @ w1 + b1), 4 bins x 4 ch per thread
        {
            float h[4][4];
            float4 bv = *(const float4*)(fb1 + (size_t)l * FILTERS + 4 * cq);
            float bva[4] = { bv.x, bv.y, bv.z, bv.w };
            #pragma unroll
            for (int aa = 0; aa < 4; aa++)
                #pragma unroll
                for (int cc = 0; cc < 4; cc++) h[aa][cc] = bva[cc];
            #pragma unroll 2
            for (int r = 0; r < NUM_RBF; r++) {
                float4 w = *(const float4*)(w1g + (size_t)r * FILTERS + 4 * cq);
                float wa[4] = { w.x, w.y, w.z, w.w };
                #pragma unroll
                for (int aa = 0; aa < 4; aa++) {
                    float rb = s_rbf[ag * 4 + aa][r];               // broadcast b32
                    #pragma unroll
                    for (int cc = 0; cc < 4; cc++) h[aa][cc] = fmaf(rb, wa[cc], h[aa][cc]);
                }
            }
            __syncthreads();                             // rbf no longer needed
            #pragma unroll
            for (int aa = 0; aa < 4; aa++) {
                float4 sv;
                sv.x = h[aa][0] / (1.f + __expf(-h[aa][0]));        // silu
                sv.y = h[aa][1] / (1.f + __expf(-h[aa][1]));
                sv.z = h[aa][2] / (1.f + __expf(-h[aa][2]));
                sv.w = h[aa][3] / (1.f + __expf(-h[aa][3]));
                *(float4*)(&s_H[ag * 4 + aa][4 * cq]) = sv;         // b128 write
            }
        }
        __syncthreads();
        // tab = (H @ w2 + b2) * env, bf16
        float o[4][4];
        float4 b2v = *(const float4*)(fb2 + (size_t)l * FILTERS + 4 * cq);
        float b2a[4] = { b2v.x, b2v.y, b2v.z, b2v.w };
        #pragma unroll
        for (int aa = 0; aa < 4; aa++)
            #pragma unroll
            for (int cc = 0; cc < 4; cc++) o[aa][cc] = b2a[cc];
        #pragma unroll 4
        for (int hh = 0; hh < FILTERS; hh += 2) {
            float4 wA = *(const float4*)(w2g + (size_t)hh * FILTERS + 4 * cq);
            float4 wB = *(const float4*)(w2g + (size_t)(hh + 1) * FILTERS + 4 * cq);
            float wa[4] = { wA.x, wA.y, wA.z, wA.w };
            float wb[4] = { wB.x, wB.y, wB.z, wB.w };
            #pragma unroll
            for (int aa = 0; aa < 4; aa++) {
                float2 hp = *(const float2*)(&s_H[ag * 4 + aa][hh]);  // broadcast b64
                #pragma unroll
                for (int cc = 0; cc < 4; cc++) {
                    o[aa][cc] = fmaf(hp.x, wa[cc], o[aa][cc]);
                    o[aa][cc] = fmaf(hp.y, wb[cc], o[aa][cc]);
                }
            }
        }
        size_t base = (size_t)l * NB4 * FILTERS;
        #pragma unroll
        for (int aa = 0; aa < 4; aa++) {
            int bin = bin0 + ag * 4 + aa;
            if (bin <= KB4) {
                float dd = bin * DSTEP;
                float env = (bin >= KB4) ? 0.f : 0.5f * (__cosf(dd * (PI_F / CUTOFF)) + 1.f);
                #pragma unroll
                for (int cp = 0; cp < 2; cp++) {
                    unsigned int pk = (unsigned)f2bf(o[aa][2 * cp] * env) |
                                      ((unsigned)f2bf(o[aa][2 * cp + 1] * env) << 16);
                    *(unsigned int*)(tab + base + (size_t)bin * FILTERS + 4 * cq + 2 * cp) = pk;
                }
            }
        }
    } else {
        // ---------------- embedding gather + xj0 = x @ d1w[0] + d1b[0], 32 atoms ----------------
        int eb = bid - TBLK;
        int i0 = eb * 32;
        if (t < 32) s_an[t] = an[i0 + t];
        __syncthreads();
        for (int idx = t; idx < 32 * HIDDEN; idx += 256) {
            int a = idx >> 7, c = idx & 127;
            float v = emb[(size_t)s_an[a] * HIDDEN + c];
            s_row[a][c] = v;
            x[(size_t)(i0 + a) * HIDDEN + c] = v;
        }
        __syncthreads();
        float o[4][4];
        float4 bv = *(const float4*)(d1b + 4 * cq);
        float bva[4] = { bv.x, bv.y, bv.z, bv.w };
        #pragma unroll
        for (int aa = 0; aa < 4; aa++)
            #pragma unroll
            for (int cc = 0; cc < 4; cc++) o[aa][cc] = bva[cc];
        #pragma unroll 4
        for (int h = 0; h < HIDDEN; h += 2) {
            float4 wA = *(const float4*)(d1w + (size_t)h * FILTERS + 4 * cq);
            float4 wB = *(const float4*)(d1w + (size_t)(h + 1) * FILTERS + 4 * cq);
            float wa[4] = { wA.x, wA.y, wA.z, wA.w };
            float wb[4] = { wB.x, wB.y, wB.z, wB.w };
            #pragma unroll
            for (int aa = 0; aa < 4; aa++) {
                float2 hp = *(const float2*)(&s_row[ag * 4 + aa][h]);
                #pragma unroll
                for (int cc = 0; cc < 4; cc++) {
                    o[aa][cc] = fmaf(hp.x, wa[cc], o[aa][cc]);
                    o[aa][cc] = fmaf(hp.y, wb[cc], o[aa][cc]);
                }
            }
        }
        #pragma unroll
        for (int aa = 0; aa < 4; aa++) {
            int i = i0 + ag * 4 + aa;
            #pragma unroll
            for (int cp = 0; cp < 2; cp++) {
                unsigned int pk = (unsigned)f2bf(o[aa][2 * cp]) |
                                  ((unsigned)f2bf(o[aa][2 * cp + 1]) << 16);
                *(unsigned int*)(xj + (size_t)i * FILTERS + 4 * cq + 2 * cp) = pk;
            }
        }
    }
}

// ======== layer: 2 j-rows per block (xj read once); nearest-bin gather (4 B/lane) ========
// (unchanged from R11 — measured ~2 us/layer). LAST merges the pool (fence-free).
template<int LAST>
__global__ void __launch_bounds__(512) k_layer(const float* __restrict__ pos,
        const unsigned int* __restrict__ tabl, const unsigned int* __restrict__ xj_in,
        float* __restrict__ x, const float* __restrict__ w2, const float* __restrict__ b2,
        const float* __restrict__ w1n, const float* __restrict__ b1n,
        unsigned short* __restrict__ xj_out,
        const int* __restrict__ batch, float* __restrict__ molsum, int* __restrict__ done,
        const float* __restrict__ ow1, const float* __restrict__ ob1,
        const float* __restrict__ ow2, const float* __restrict__ ob2,
        float* __restrict__ out) {
    int bid = blockIdx.x, t = threadIdx.x;
    int j0 = 2 * bid, j1 = j0 + 1;
    int wv = t >> 6, e = t & 63;
    __shared__ unsigned int s_bin[N_ATOMS];              // 2 KB: bins to j0 | j1<<16
    __shared__ float s_part[2][8][FILTERS];              // 8 KB
    __shared__ float s_red[4][FILTERS];
    __shared__ float s_agg[2][FILTERS];
    __shared__ float s_xn[2][HIDDEN];
    __shared__ int   s_cnt;
    {   // two distances per thread
        float px = pos[3*t], py = pos[3*t+1], pz = pos[3*t+2];
        float ax = pos[3*j0], ay = pos[3*j0+1], az = pos[3*j0+2];
        float bx = pos[3*j1], by = pos[3*j1+1], bz = pos[3*j1+2];
        float d0 = sqrtf((px-ax)*(px-ax) + (py-ay)*(py-ay) + (pz-az)*(pz-az));
        float d1 = sqrtf((px-bx)*(px-bx) + (py-by)*(py-by) + (pz-bz)*(pz-bz));
        unsigned int b0 = (t == j0 || d0 >= CUTOFF) ? KB4 : (unsigned)(int)fmaf(d0, DINV, 0.5f);
        unsigned int b1 = (t == j1 || d1 >= CUTOFF) ? KB4 : (unsigned)(int)fmaf(d1, DINV, 0.5f);
        if (b0 > KB4) b0 = KB4;
        if (b1 > KB4) b1 = KB4;
        s_bin[t] = b0 | (b1 << 16);
    }
    int c = t & 127, seg = t >> 7, jj = seg >> 1, sub = seg & 1;
    float xold = (sub == 0) ? x[(size_t)(jj ? j1 : j0) * HIDDEN + c] : 0.f;
    __syncthreads();
    // ---- aggregation: wave wv covers i in [wv*64,+64) for BOTH j's ----
    float a0e = 0.f, a0o = 0.f, a1e = 0.f, a1o = 0.f;
    int i0 = wv * 64;
    for (int ii = 0; ii < 64; ii += 4) {
        #pragma unroll
        for (int r = 0; r < 4; r++) {
            unsigned int pk = s_bin[i0 + ii + r];
            unsigned int bb0 = pk & 0xffffu, bb1 = pk >> 16;
            unsigned int xu = xj_in[(size_t)(i0 + ii + r) * 64 + e];
            unsigned int f0 = tabl[(size_t)bb0 * 64 + e];
            unsigned int f1 = tabl[(size_t)bb1 * 64 + e];
            float xe = __uint_as_float(xu << 16), xo = __uint_as_float(xu & 0xffff0000u);
            float p0e = __uint_as_float(f0 << 16), p0o = __uint_as_float(f0 & 0xffff0000u);
            float p1e = __uint_as_float(f1 << 16), p1o = __uint_as_float(f1 & 0xffff0000u);
            a0e = fmaf(xe, p0e, a0e);  a0o = fmaf(xo, p0o, a0o);
            a1e = fmaf(xe, p1e, a1e);  a1o = fmaf(xo, p1o, a1o);
        }
    }
    s_part[0][wv][2*e] = a0e;  s_part[0][wv][2*e+1] = a0o;
    s_part[1][wv][2*e] = a1e;  s_part[1][wv][2*e+1] = a1o;
    __syncthreads();
    if (t < 256) {
        int pj = t >> 7, cc = t & 127;
        float s = 0.f;
        #pragma unroll
        for (int w8 = 0; w8 < 8; w8++) s += s_part[pj][w8][cc];
        s_agg[pj][cc] = s;
    }
    __syncthreads();
    // ---- x update: seg {0,1}->j0, {2,3}->j1; sub splits the 128-dot 64/64 ----
    float v = 0.f;
    #pragma unroll 8
    for (int ff = sub * 64; ff < sub * 64 + 64; ff++)
        v = fmaf(s_agg[jj][ff], w2[(size_t)ff * HIDDEN + c], v);
    s_red[seg][c] = v;
    __syncthreads();
    float xnew = 0.f;
    if (sub == 0) {
        xnew = xold + b2[c] + s_red[jj*2][c] + s_red[jj*2+1][c];
        x[(size_t)(jj ? j1 : j0) * HIDDEN + c] = xnew;
        s_xn[jj][c] = xnew;
    }
    __syncthreads();
    if (!LAST) {
        float a2 = 0.f;
        #pragma unroll 8
        for (int hh = sub * 64; hh < sub * 64 + 64; hh++)
            a2 = fmaf(s_xn[jj][hh], w1n[(size_t)hh * FILTERS + c], a2);
        s_red[seg][c] = a2;
        __syncthreads();
        if (sub == 0)
            xj_out[(size_t)(jj ? j1 : j0) * FILTERS + c] =
                f2bf(b1n[c] + s_red[jj*2][c] + s_red[jj*2+1][c]);
    } else {
        // ---- pool tail: device atomics; __syncthreads drains vmcnt before done++ ----
        if (sub == 0) atomicAdd(&molsum[(size_t)batch[jj ? j1 : j0] * HIDDEN + c], xnew);
        __syncthreads();
        if (t == 0) atomicAdd(done, 1);
        if (bid < N_MOL) {
            int m = bid;
            if (t == 0) {
                while (atomicAdd(done, 0) < N_ATOMS / 2) __builtin_amdgcn_s_sleep(16);
                s_cnt = 0;
            }
            __syncthreads();
            atomicAdd(&s_cnt, (batch[t] == m) ? 1 : 0);
            __syncthreads();
            int cnt = s_cnt;
            if (t < HIDDEN)
                s_xn[0][t] = atomicAdd(&molsum[(size_t)m * HIDDEN + t], 0.f)
                           / (float)(cnt > 0 ? cnt : 1);
            __syncthreads();
            int o = t & 63, sl = t >> 6;                  // 8 slices x 16 terms
            float a = 0.f;
            #pragma unroll 8
            for (int h = sl * 16; h < sl * 16 + 16; h++)
                a = fmaf(s_xn[0][h], ow1[h * 64 + o], a);
            float* sr = (float*)s_part;                   // reuse as [8][64]
            sr[sl * 64 + o] = a;
            __syncthreads();
            if (t < 64) {
                float vv = ob1[t];
                #pragma unroll
                for (int s8 = 0; s8 < 8; s8++) vv += sr[s8 * 64 + t];
                float hh = vv / (1.f + __expf(-vv));      // silu
                float d2 = hh * ow2[t];
                for (int off = 32; off > 0; off >>= 1) d2 += __shfl_down(d2, off, 64);
                if (t == 0) out[m] = d2 + ob2[0];
            }
        }
    }
}

extern "C" void kernel_launch(void* const* d_in, const int* in_sizes, int n_in,
                              void* d_out, int out_size, void* d_ws, size_t ws_size,
                              hipStream_t stream) {
    const int*   an    = (const int*)  d_in[0];
    const float* pos   = (const float*)d_in[1];
    const int*   batch = (const int*)  d_in[2];
    const float* emb   = (const float*)d_in[3];
    const float* fw1   = (const float*)d_in[4];
    const float* fb1   = (const float*)d_in[5];
    const float* fw2   = (const float*)d_in[6];
    const float* fb2   = (const float*)d_in[7];
    const float* d1w   = (const float*)d_in[8];
    const float* d1b   = (const float*)d_in[9];
    const float* d2w   = (const float*)d_in[10];
    const float* d2b   = (const float*)d_in[11];
    const float* ow1   = (const float*)d_in[12];
    const float* ob1   = (const float*)d_in[13];
    const float* ow2   = (const float*)d_in[14];
    const float* ob2   = (const float*)d_in[15];
    float* out = (float*)d_out;

    float*          x    = (float*)d_ws;                               // 256 KB
    unsigned short* xjA  = (unsigned short*)(x + N_ATOMS * HIDDEN);    // 128 KB
    unsigned short* xjB  = xjA + (size_t)N_ATOMS * FILTERS;            // 128 KB
    unsigned short* tab  = xjB + (size_t)N_ATOMS * FILTERS;            // 3.07 MB
    float*          mols = (float*)(tab + (size_t)N_LAYERS * NB4 * FILTERS);
    int*            done = (int*)(mols + N_MOL * HIDDEN);

    k_front<<<TBLK + EMBB, 256, 0, stream>>>(
        an, emb, d1w, d1b, fw1, fb1, fw2, fb2, x, xjA, tab, mols, done);

    const unsigned int* t0 = (const unsigned int*)(tab + (size_t)0 * NB4 * FILTERS);
    const unsigned int* t1 = (const unsigned int*)(tab + (size_t)1 * NB4 * FILTERS);
    const unsigned int* t2 = (const unsigned int*)(tab + (size_t)2 * NB4 * FILTERS);

    k_layer<0><<<N_ATOMS/2, 512, 0, stream>>>(pos, t0, (const unsigned int*)xjA, x,
        d2w + (size_t)0*FILTERS*HIDDEN, d2b + (size_t)0*HIDDEN,
        d1w + (size_t)1*HIDDEN*FILTERS, d1b + (size_t)1*FILTERS, xjB,
        batch, mols, done, ow1, ob1, ow2, ob2, out);
    k_layer<0><<<N_ATOMS/2, 512, 0, stream>>>(pos, t1, (const unsigned int*)xjB, x,
        d2w + (size_t)1*FILTERS*HIDDEN, d2b + (size_t)1*HIDDEN,
        d1w + (size_t)2*HIDDEN*FILTERS, d1b + (size_t)2*FILTERS, xjA,
        batch, mols, done, ow1, ob1, ow2, ob2, out);
    k_layer<1><<<N_ATOMS/2, 512, 0, stream>>>(pos, t2, (const unsigned int*)xjA, x,
        d2w + (size_t)2*FILTERS*HIDDEN, d2b + (size_t)2*HIDDEN,
        d1w, d1b, xjB,
        batch, mols, done, ow1, ob1, ow2, ob2, out);
}